// Round 6
// baseline (325.922 us; speedup 1.0000x reference)
//
#include <hip/hip_runtime.h>

#define DIM   1024
#define HEADS 16
#define HD    64
#define BB    2
#define SS    2048
#define LLL   2048
#define LOG2E 1.4426950408889634f

typedef __bf16 bf16x8 __attribute__((ext_vector_type(8)));
typedef __bf16 bf16x4v __attribute__((ext_vector_type(4)));
typedef float  f32x4  __attribute__((ext_vector_type(4)));
typedef short  s16x4  __attribute__((ext_vector_type(4)));
typedef short  s16x8  __attribute__((ext_vector_type(8)));
typedef unsigned short u16;

static __device__ __forceinline__ u16 f2b(float x) {
  unsigned u = __float_as_uint(x);
  u += 0x7fffu + ((u >> 16) & 1u);
  return (u16)(u >> 16);
}
static __device__ __forceinline__ float b2f(u16 u) {
  return __uint_as_float(((unsigned)u) << 16);
}
static __device__ __forceinline__ f32x4 mfma32(bf16x8 a, bf16x8 b, f32x4 c) {
  return __builtin_amdgcn_mfma_f32_16x16x32_bf16(a, b, c, 0, 0, 0);
}
static __device__ __forceinline__ f32x4 mfma16(s16x4 a, s16x4 b, f32x4 c) {
#if __has_builtin(__builtin_amdgcn_mfma_f32_16x16x16bf16_1k)
  return __builtin_amdgcn_mfma_f32_16x16x16bf16_1k(a, b, c, 0, 0, 0);
#else
  asm volatile("v_mfma_f32_16x16x16_bf16 %0, %1, %2, %0" : "+v"(c) : "v"(a), "v"(b));
  return c;
#endif
}

// ---------------- f32 -> bf16 convert ----------------
__global__ void cvt_f32_bf16(const float* __restrict__ src, u16* __restrict__ dst, int n4) {
  int i = blockIdx.x * blockDim.x + threadIdx.x;
  if (i >= n4) return;
  float4 f = ((const float4*)src)[i];
  ushort4 o;
  o.x = f2b(f.x); o.y = f2b(f.y); o.z = f2b(f.z); o.w = f2b(f.w);
  ((ushort4*)dst)[i] = o;
}

// ---------------- mask -> bitmask ----------------
__global__ void mask_pack(const int* __restrict__ mask, unsigned* __restrict__ mbits) {
  int i = blockIdx.x * blockDim.x + threadIdx.x;
  const int* src = mask + (size_t)i * 32;
  unsigned bm = 0;
#pragma unroll
  for (int j = 0; j < 8; ++j) {
    int4 m = ((const int4*)src)[j];
    bm |= (m.x != 0 ? 1u : 0u) << (j * 4 + 0);
    bm |= (m.y != 0 ? 1u : 0u) << (j * 4 + 1);
    bm |= (m.z != 0 ? 1u : 0u) << (j * 4 + 2);
    bm |= (m.w != 0 ? 1u : 0u) << (j * 4 + 3);
  }
  mbits[i] = bm;
}

// ---------------- K (f32) -> fragment-packed bf16 tiles, PRESCALED by 0.125*log2(e) ----------------
// Kfrag[z][h][lt][c=mt*2+kk][lane][8]: lane(g,li) holds SC*K[lt*64+mt*16+li][h*64+kk*32+g*8..+7]
__global__ __launch_bounds__(256) void pack_k(const float* __restrict__ k0,
                                              const float* __restrict__ k1,
                                              u16* __restrict__ Kfrag) {
  const float SCK = 0.125f * LOG2E;
  const int w = threadIdx.x >> 6, l = threadIdx.x & 63, g = l >> 4, li = l & 15;
  const int lt = blockIdx.x * 4 + w, h = blockIdx.y, z = blockIdx.z;
  const int lay = z >> 1, b = z & 1;
  const float* src = (lay ? k1 : k0) + (size_t)b * LLL * DIM;
  u16* dst = Kfrag + ((((size_t)z * HEADS + h) * 32 + lt) * 8) * 512;
#pragma unroll
  for (int c = 0; c < 8; ++c) {
    int mt = c >> 1, kk = c & 1;
    const float* p = &src[(size_t)(lt * 64 + mt * 16 + li) * DIM + h * 64 + kk * 32 + g * 8];
    float4 f0 = *(const float4*)p;
    float4 f1 = *(const float4*)(p + 4);
    u16 u[8] = {f2b(f0.x * SCK), f2b(f0.y * SCK), f2b(f0.z * SCK), f2b(f0.w * SCK),
                f2b(f1.x * SCK), f2b(f1.y * SCK), f2b(f1.z * SCK), f2b(f1.w * SCK)};
    *(uint4*)&dst[c * 512 + l * 8] = *(uint4*)u;
  }
}

// ---------------- V (f32) -> fragment-packed bf16 tiles (transposed) ----------------
__global__ __launch_bounds__(256) void pack_v(const float* __restrict__ v0,
                                              const float* __restrict__ v1,
                                              u16* __restrict__ Vfrag) {
  __shared__ u16 T[64][72];  // T[l][d]
  const int lt = blockIdx.x, h = blockIdx.y, z = blockIdx.z;
  const int lay = z >> 1, b = z & 1;
  const float* v = (lay ? v1 : v0) + (size_t)b * LLL * DIM;
  const int t = threadIdx.x;
  {
    int r = t >> 2, c16 = (t & 3) * 16;
    const float* src = &v[(size_t)(lt * 64 + r) * DIM + h * 64 + c16];
#pragma unroll
    for (int i = 0; i < 4; ++i) {
      float4 f = *(const float4*)&src[i * 4];
      T[r][c16 + i * 4 + 0] = f2b(f.x);
      T[r][c16 + i * 4 + 1] = f2b(f.y);
      T[r][c16 + i * 4 + 2] = f2b(f.z);
      T[r][c16 + i * 4 + 3] = f2b(f.w);
    }
  }
  __syncthreads();
  u16* dst = Vfrag + ((((size_t)z * HEADS + h) * 32 + lt) * 8) * 512;
  {
    int lane = t & 63, g = lane >> 4, li = lane & 15;
#pragma unroll
    for (int cc = 0; cc < 2; ++cc) {
      int c = (t >> 6) + cc * 4;
      int mt = c >> 1, p = c & 1;
      u16 u[8];
#pragma unroll
      for (int j = 0; j < 4; ++j) u[j] = T[mt * 16 + 4 * g + j][p * 32 + li];
#pragma unroll
      for (int j = 0; j < 4; ++j) u[4 + j] = T[mt * 16 + 4 * g + j][p * 32 + 16 + li];
      *(uint4*)&dst[c * 512 + lane * 8] = *(uint4*)u;
    }
  }
}

// ---------------- bf16 NT GEMM, 128x64 tile. MODE 1: f32 row-major out; MODE 2: Q-fragment out
template<int MODE>
__global__ __launch_bounds__(256) void gemm_nt(const u16* __restrict__ A,
                                               const u16* __restrict__ Bt,
                                               const float* __restrict__ bias,
                                               void* __restrict__ Cv,
                                               int M, int N, int K) {
  __shared__ u16 As[128][64];
  __shared__ u16 Bs[64][64];
  const int t = threadIdx.x;
  const int w = t >> 6, l = t & 63, g = l >> 4, li = l & 15;
  const int m0 = blockIdx.y * 128, n0 = blockIdx.x * 64;
  f32x4 acc[2][4] = {};
  for (int kt = 0; kt < K; kt += 64) {
#pragma unroll
    for (int s = 0; s < 4; ++s) {
      int slot = t + s * 256;
      int r = slot >> 3, c8 = (slot & 7) * 8;
      *(uint4*)&As[r][c8 ^ ((r & 7) << 3)] = *(const uint4*)&A[(size_t)(m0 + r) * K + kt + c8];
    }
#pragma unroll
    for (int s = 0; s < 2; ++s) {
      int slot = t + s * 256;
      int r = slot >> 3, c8 = (slot & 7) * 8;
      *(uint4*)&Bs[r][c8 ^ ((r & 7) << 3)] = *(const uint4*)&Bt[(size_t)(n0 + r) * K + kt + c8];
    }
    __syncthreads();
#pragma unroll
    for (int kk = 0; kk < 2; ++kk) {
      bf16x8 a[2], bfr[4];
#pragma unroll
      for (int mi = 0; mi < 2; ++mi) {
        int ra = w * 32 + mi * 16 + li;
        a[mi] = *(const bf16x8*)&As[ra][(kk * 32 + g * 8) ^ ((ra & 7) << 3)];
      }
#pragma unroll
      for (int ni = 0; ni < 4; ++ni) {
        int rb = ni * 16 + li;
        bfr[ni] = *(const bf16x8*)&Bs[rb][(kk * 32 + g * 8) ^ ((rb & 7) << 3)];
      }
#pragma unroll
      for (int mi = 0; mi < 2; ++mi)
#pragma unroll
        for (int ni = 0; ni < 4; ++ni)
          acc[mi][ni] = mfma32(a[mi], bfr[ni], acc[mi][ni]);
    }
    __syncthreads();
  }
#pragma unroll
  for (int mi = 0; mi < 2; ++mi)
#pragma unroll
    for (int ni = 0; ni < 4; ++ni)
#pragma unroll
      for (int v = 0; v < 4; ++v) {
        int rr = m0 + w * 32 + mi * 16 + g * 4 + v;
        int cc = n0 + ni * 16 + li;
        float val = acc[mi][ni][v] + bias[cc];
        if (MODE == 1) {
          ((float*)Cv)[(size_t)rr * N + cc] = val;
        } else {
          // Qfrag[b][h][qt][c=n*2+kk][lane(gp,liq)][8]
          int b = rr >> 11, q = rr & 2047;
          int qt = q >> 5, n = (q >> 4) & 1, liq = q & 15;
          int h = (cc >> 6) & 15, kk2 = (cc >> 5) & 1, gp = (cc >> 3) & 3, j = cc & 7;
          size_t base = ((((size_t)b * HEADS + h) * 64 + qt) * 4 + n * 2 + kk2) * 512;
          ((u16*)Cv)[base + (size_t)(gp * 16 + liq) * 8 + j] = f2b(val);
        }
      }
}

// ---------------- attn_pv: one pass, 16 q-rows per wave, no LDS/barriers ----------------
template<int MASKED>
static __device__ __forceinline__ void attn_pv_body(int z, int h, int qt2, int l,
                                                    const u16* __restrict__ Qfrag,
                                                    const u16* __restrict__ Kfrag,
                                                    const u16* __restrict__ Vfrag,
                                                    const unsigned* __restrict__ mbits,
                                                    u16* __restrict__ out01,
                                                    float* __restrict__ db) {
  const int g = l >> 4, li = l & 15;
  const int b = z & 1;
  const int qt = qt2 >> 1, n = qt2 & 1;
  const u16* kfh = Kfrag + (size_t)(z * HEADS + h) * (32 * 8 * 512);
  const u16* vfh = Vfrag + (size_t)(z * HEADS + h) * (32 * 8 * 512);
  const u16* qfh = Qfrag + ((((size_t)(b * HEADS + h) * 64 + qt) * 4 + n * 2)) * 512;

  bf16x8 qf[2];
  qf[0] = *(const bf16x8*)&qfh[0 * 512 + l * 8];
  qf[1] = *(const bf16x8*)&qfh[1 * 512 + l * 8];

  const unsigned* mrow = MASKED ? mbits + (size_t)(qt2 * 16 + li) * (LLL / 32) : nullptr;
  const int shb = 4 * g;

  f32x4 racc4 = {};
  f32x4 oacc[4] = {};  // [dt], unnormalized
  for (int lt = 0; lt < 32; ++lt) {
    unsigned mw[2];
    if (MASKED) { mw[0] = mrow[lt * 2]; mw[1] = mrow[lt * 2 + 1]; }
    const u16* kfl = kfh + (size_t)lt * 4096 + l * 8;
    const u16* vfl = vfh + (size_t)lt * 4096 + l * 8;
#pragma unroll
    for (int mt = 0; mt < 4; ++mt) {
      f32x4 s = {};
      __builtin_amdgcn_s_setprio(1);
      s = mfma32(*(const bf16x8*)&kfl[(mt * 2 + 0) * 512], qf[0], s);
      s = mfma32(*(const bf16x8*)&kfl[(mt * 2 + 1) * 512], qf[1], s);
      __builtin_amdgcn_s_setprio(0);
      f32x4 ev;
      unsigned mm = MASKED ? (mw[mt >> 1] >> ((mt & 1) * 16 + shb)) : 0u;
#pragma unroll
      for (int v = 0; v < 4; ++v) {
        float arg = s[v];
        if (MASKED) {
          int spread = ((int)(mm << (31 - v))) >> 31;  // all-ones if keep
          float bias = __uint_as_float((~(unsigned)spread) & 0xC3200000u);  // -160 if drop
          arg = s[v] + bias;
        }
        ev[v] = __builtin_amdgcn_exp2f(arg);
      }
      racc4 += ev;
      bf16x4v wb = __builtin_convertvector(ev, bf16x4v);
      s16x4 wpk = __builtin_bit_cast(s16x4, wb);
      __builtin_amdgcn_s_setprio(1);
#pragma unroll
      for (int p = 0; p < 2; ++p) {
        s16x8 vf = *(const s16x8*)&vfl[(mt * 2 + p) * 512];
        s16x4 lo = __builtin_shufflevector(vf, vf, 0, 1, 2, 3);
        s16x4 hi = __builtin_shufflevector(vf, vf, 4, 5, 6, 7);
        oacc[2 * p + 0] = mfma16(lo, wpk, oacc[2 * p + 0]);
        oacc[2 * p + 1] = mfma16(hi, wpk, oacc[2 * p + 1]);
      }
      __builtin_amdgcn_s_setprio(0);
    }
  }
  float r = racc4[0] + racc4[1] + racc4[2] + racc4[3];
  r += __shfl_xor(r, 16);
  r += __shfl_xor(r, 32);
  float dinv = 1.0f / r;
  if (l < 16) db[(size_t)(z * HEADS + h) * SS + qt2 * 16 + li] = dinv;
  u16* ob = out01 + (size_t)z * SS * DIM;
#pragma unroll
  for (int dt = 0; dt < 4; ++dt) {
    f32x4 o = oacc[dt] * dinv;
    ushort4 us;
    us.x = f2b(o[0]); us.y = f2b(o[1]); us.z = f2b(o[2]); us.w = f2b(o[3]);
    *(ushort4*)&ob[((size_t)(qt2 * 16 + li)) * DIM + h * HD + dt * 16 + 4 * g] = us;
  }
}

__global__ __launch_bounds__(256, 8) void attn_pv(const u16* __restrict__ Qfrag,
                                                  const u16* __restrict__ Kfrag,
                                                  const u16* __restrict__ Vfrag,
                                                  const unsigned* __restrict__ mbits,
                                                  u16* __restrict__ out01,
                                                  float* __restrict__ db) {
  const int flat = blockIdx.x;
  const int wb = (flat & 7) * 256 + (flat >> 3);   // XCD-contiguous chunks (2048 blocks)
  const int widx = wb * 4 + (threadIdx.x >> 6);    // 8192 waves
  const int z = widx >> 11, rem = widx & 2047;
  const int h = rem >> 7, qt2 = rem & 127;         // block = 4 qt2 of same (z,h): share K/V
  if (z < 2) attn_pv_body<1>(z, h, qt2, threadIdx.x & 63, Qfrag, Kfrag, Vfrag, mbits, out01, db);
  else       attn_pv_body<0>(z, h, qt2, threadIdx.x & 63, Qfrag, Kfrag, Vfrag, mbits, out01, db);
}

// ---------------- amean: head-mean map; one wave = all 16 heads of one 16x64 S-tile ----------------
template<int MASKED>
static __device__ __forceinline__ void amean_body(int z, int qt2, int lt, int l,
                                                  const u16* __restrict__ Qfrag,
                                                  const u16* __restrict__ Kfrag,
                                                  const unsigned* __restrict__ mbits,
                                                  const float* __restrict__ db,
                                                  float* __restrict__ aout) {
  const int g = l >> 4, li = l & 15;
  const int b = z & 1;
  const int qt = qt2 >> 1, n = qt2 & 1;

  unsigned mw[2];
  if (MASKED) {
    const unsigned* m0 = mbits + (size_t)(qt2 * 16 + li) * (LLL / 32) + lt * 2;
    mw[0] = m0[0]; mw[1] = m0[1];
  }
  const u16* kf_base = Kfrag + (size_t)(z * HEADS) * (32 * 8 * 512) + (size_t)lt * 4096 + l * 8;
  const u16* qf_base = Qfrag + ((((size_t)(b * HEADS) * 64 + qt) * 4 + n * 2)) * 512 + l * 8;
  const float* dbb = db + (size_t)(z * HEADS) * SS + qt2 * 16 + li;

  f32x4 asum[4] = {};
#pragma unroll 2
  for (int h = 0; h < HEADS; ++h) {
    float l2 = __log2f(dbb[(size_t)h * SS]);
    bf16x8 qf0 = *(const bf16x8*)&qf_base[(size_t)h * (64 * 4 * 512)];
    bf16x8 qf1 = *(const bf16x8*)&qf_base[(size_t)h * (64 * 4 * 512) + 512];
    const u16* kfh = kf_base + (size_t)h * (32 * 8 * 512);
#pragma unroll
    for (int mt = 0; mt < 4; ++mt) {
      f32x4 s = {};
      s = mfma32(*(const bf16x8*)&kfh[(mt * 2 + 0) * 512], qf0, s);
      s = mfma32(*(const bf16x8*)&kfh[(mt * 2 + 1) * 512], qf1, s);
      unsigned mm = MASKED ? (mw[mt >> 1] >> ((mt & 1) * 16 + 4 * g)) : 0u;
#pragma unroll
      for (int v = 0; v < 4; ++v) {
        float bias = l2;
        if (MASKED && !((mm >> v) & 1u)) bias = -160.0f;
        asum[mt][v] += __builtin_amdgcn_exp2f(s[v] + bias);
      }
    }
  }
  float* ab = aout + (size_t)z * SS * LLL;
#pragma unroll
  for (int mt = 0; mt < 4; ++mt) {
    f32x4 o = asum[mt] * 0.0625f;
    f32x4* dst = (f32x4*)&ab[(size_t)(qt2 * 16 + li) * LLL + lt * 64 + mt * 16 + 4 * g];
    __builtin_nontemporal_store(o, dst);
  }
}

__global__ __launch_bounds__(256, 8) void amean(const u16* __restrict__ Qfrag,
                                                const u16* __restrict__ Kfrag,
                                                const unsigned* __restrict__ mbits,
                                                const float* __restrict__ db,
                                                float* __restrict__ aout) {
  const int flat = blockIdx.x;
  const int wb = (flat & 7) * 512 + (flat >> 3);   // XCD-contiguous chunks (4096 blocks)
  const int widx = wb * 4 + (threadIdx.x >> 6);    // 16384 waves
  const int z = widx >> 12, rem = widx & 4095;
  const int lt = rem >> 7, qt2 = rem & 127;        // block = 4 qt2 of same (z,lt): share K tile
  if (z < 2) amean_body<1>(z, qt2, lt, threadIdx.x & 63, Qfrag, Kfrag, mbits, db, aout);
  else       amean_body<0>(z, qt2, lt, threadIdx.x & 63, Qfrag, Kfrag, mbits, db, aout);
}

// ---------------- gated merge ----------------
__global__ void merge_kernel(const u16* __restrict__ o01,
                             const float* __restrict__ gate,
                             u16* __restrict__ merged) {
  int i = blockIdx.x * blockDim.x + threadIdx.x;
  float gv = gate[0];
  float g = 1.0f / (1.0f + __builtin_amdgcn_exp2f(-gv * LOG2E));
  const size_t n = (size_t)BB * SS * DIM;
  ushort4 a = ((const ushort4*)o01)[i];
  ushort4 c = ((const ushort4*)(o01 + n))[i];
  ushort4 o;
  o.x = f2b(g * b2f(a.x) + (1.f - g) * b2f(c.x));
  o.y = f2b(g * b2f(a.y) + (1.f - g) * b2f(c.y));
  o.z = f2b(g * b2f(a.z) + (1.f - g) * b2f(c.z));
  o.w = f2b(g * b2f(a.w) + (1.f - g) * b2f(c.w));
  ((ushort4*)merged)[i] = o;
}

extern "C" void kernel_launch(void* const* d_in, const int* in_sizes, int n_in,
                              void* d_out, int out_size, void* d_ws, size_t ws_size,
                              hipStream_t stream) {
  const float* query = (const float*)d_in[0];
  const float* k0f   = (const float*)d_in[1];
  const float* v0f   = (const float*)d_in[2];
  const float* k1f   = (const float*)d_in[3];
  const float* v1f   = (const float*)d_in[4];
  const int*   mask  = (const int*)d_in[5];
  const float* Wqf   = (const float*)d_in[6];
  const float* bq    = (const float*)d_in[7];
  const float* Wof   = (const float*)d_in[8];
  const float* bo    = (const float*)d_in[9];
  const float* gate  = (const float*)d_in[10];
  float* out = (float*)d_out;

  const size_t nQ = (size_t)BB * SS * DIM;
  const size_t nW = (size_t)DIM * DIM;

  char* ws = (char*)d_ws;
  size_t off = 0;
  auto alloc = [&](size_t bytes) -> char* {
    char* p = ws + off;
    off += (bytes + 255) & ~(size_t)255;
    return p;
  };
  u16*      queryb  = (u16*)alloc(nQ * 2);             // reused as mergedb later
  u16*      wqb     = (u16*)alloc(nW * 2);
  u16*      wob     = (u16*)alloc(nW * 2);
  u16*      Qfrag   = (u16*)alloc(nQ * 2);             // [b][h][qt][c][lane][8]
  u16*      Kfrag   = (u16*)alloc((size_t)2 * nQ * 2); // [z][h][lt][c][lane][8] (prescaled)
  u16*      Vfrag   = (u16*)alloc((size_t)2 * nQ * 2);
  unsigned* mbits   = (unsigned*)alloc((size_t)SS * (LLL / 32) * 4);
  float*    db      = (float*)alloc((size_t)4 * HEADS * SS * 4);  // dinv per (z,h,q)
  u16*      out01   = (u16*)alloc((size_t)2 * nQ * 2);
  u16*      mergedb = queryb;  // queryb dead after q-proj gemm

  auto cvt = [&](const float* s, u16* d, size_t n) {
    int n4 = (int)(n / 4);
    cvt_f32_bf16<<<dim3((n4 + 255) / 256), dim3(256), 0, stream>>>(s, d, n4);
  };
  cvt(query, queryb, nQ);
  cvt(Wqf, wqb, nW);
  cvt(Wof, wob, nW);

  mask_pack<<<dim3(SS * (LLL / 32) / 256), dim3(256), 0, stream>>>(mask, mbits);
  pack_k<<<dim3(LLL / 64 / 4, HEADS, 4), dim3(256), 0, stream>>>(k0f, k1f, Kfrag);
  pack_v<<<dim3(LLL / 64, HEADS, 4), dim3(256), 0, stream>>>(v0f, v1f, Vfrag);

  // q projection straight into fragment layout (128x64 tiles)
  gemm_nt<2><<<dim3(DIM / 64, (BB * SS) / 128), dim3(256), 0, stream>>>(
      queryb, wqb, bq, (void*)Qfrag, BB * SS, DIM, DIM);

  // fused single-pass attention (O + dinv), fully per-wave, 16 rows/wave
  attn_pv<<<dim3(2048), dim3(256), 0, stream>>>(Qfrag, Kfrag, Vfrag, mbits, out01, db);

  // head-mean attention maps straight into d_out, 16 rows/wave
  amean<<<dim3(4096), dim3(256), 0, stream>>>(Qfrag, Kfrag, mbits, db, out + nQ);

  merge_kernel<<<dim3((int)(nQ / 4 / 256)), dim3(256), 0, stream>>>(out01, gate, mergedb);

  gemm_nt<1><<<dim3(DIM / 64, (BB * SS) / 128), dim3(256), 0, stream>>>(
      mergedb, wob, bo, (void*)out, BB * SS, DIM, DIM);
}